// Round 1
// baseline (341.909 us; speedup 1.0000x reference)
//
#include <hip/hip_runtime.h>

#define L_DIM 1024
#define B_DIM 256
#define D_DIM 768
#define H_DIM 768

// ---------------------------------------------------------------------------
// K1: for each row l: reduce over B (masked + total), build
//   V[l]       = 0.5 * pos_sum/max(cnt,1)       + 0.5 * gpt[l]
//   V[L + l]   = 0.5 * (tot-pos)/max(B-cnt,1)   + 0.5 * gpt[L]
// and write pos_cnt[l] (as float).
// grid = L blocks, 192 threads (each thread owns 4 consecutive d via float4).
// ---------------------------------------------------------------------------
__global__ __launch_bounds__(192)
void reduce_build_v(const float* __restrict__ x,
                    const int* __restrict__ mask,
                    const float* __restrict__ gpt,
                    float* __restrict__ V,
                    float* __restrict__ pos_cnt)
{
    const int l  = blockIdx.x;
    const int d0 = threadIdx.x * 4;

    float4 pos = make_float4(0.f, 0.f, 0.f, 0.f);
    float4 tot = make_float4(0.f, 0.f, 0.f, 0.f);
    int cnt = 0;

    const float* xp = x + (size_t)l * D_DIM + d0;
    const size_t bstride = (size_t)L_DIM * D_DIM;

    #pragma unroll 4
    for (int b = 0; b < B_DIM; ++b) {
        const int m = mask[b * L_DIM + l];          // uniform across block
        const float fm = (float)m;
        const float4 v = *(const float4*)(xp + (size_t)b * bstride);
        tot.x += v.x; tot.y += v.y; tot.z += v.z; tot.w += v.w;
        pos.x = fmaf(fm, v.x, pos.x);
        pos.y = fmaf(fm, v.y, pos.y);
        pos.z = fmaf(fm, v.z, pos.z);
        pos.w = fmaf(fm, v.w, pos.w);
        cnt += m;
    }

    const float inv_p = 0.5f / fmaxf((float)cnt, 1.0f);
    const float inv_a = 0.5f / fmaxf((float)(B_DIM - cnt), 1.0f);

    const float4 g  = *(const float4*)(gpt + (size_t)l * D_DIM + d0);
    const float4 gl = *(const float4*)(gpt + (size_t)L_DIM * D_DIM + d0);

    float4 vp, va;
    vp.x = pos.x * inv_p + 0.5f * g.x;
    vp.y = pos.y * inv_p + 0.5f * g.y;
    vp.z = pos.z * inv_p + 0.5f * g.z;
    vp.w = pos.w * inv_p + 0.5f * g.w;
    va.x = (tot.x - pos.x) * inv_a + 0.5f * gl.x;
    va.y = (tot.y - pos.y) * inv_a + 0.5f * gl.y;
    va.z = (tot.z - pos.z) * inv_a + 0.5f * gl.z;
    va.w = (tot.w - pos.w) * inv_a + 0.5f * gl.w;

    *(float4*)(V + (size_t)l * D_DIM + d0)            = vp;
    *(float4*)(V + (size_t)(L_DIM + l) * D_DIM + d0)  = va;

    if (threadIdx.x == 0) pos_cnt[l] = (float)cnt;
}

// ---------------------------------------------------------------------------
// Tiled fp32 GEMM: C[M,N] = A[M,K] @ B[N,K]^T + bias[N], optional ReLU.
// Both A and B are row-major with K contiguous -> coalesced global loads.
// BM=BN=64, BK=16; 256 threads; 4x4 micro-tile per thread.
// ---------------------------------------------------------------------------
#define BM 64
#define BN 64
#define BK 16

template<bool RELU>
__global__ __launch_bounds__(256)
void gemm_atbt(const float* __restrict__ A,
               const float* __restrict__ Bm,
               const float* __restrict__ bias,
               float* __restrict__ C,
               int M, int N, int K)
{
    __shared__ float As[BK][BM];
    __shared__ float Bs[BK][BN];

    const int tid  = threadIdx.x;
    const int brow = blockIdx.y * BM;
    const int bcol = blockIdx.x * BN;
    const int tx = tid & 15;     // 0..15 -> 4 cols each
    const int ty = tid >> 4;     // 0..15 -> 4 rows each

    // staging indices: each thread loads one float4 of A and one of B per K-tile
    const int lr = tid >> 2;          // 0..63 row within tile
    const int lk = (tid & 3) * 4;     // k offset 0,4,8,12

    float c[4][4];
    #pragma unroll
    for (int i = 0; i < 4; ++i)
        #pragma unroll
        for (int j = 0; j < 4; ++j) c[i][j] = 0.f;

    const float* Ap = A + (size_t)(brow + lr) * K + lk;
    const float* Bp = Bm + (size_t)(bcol + lr) * K + lk;

    for (int k0 = 0; k0 < K; k0 += BK) {
        const float4 av = *(const float4*)(Ap + k0);
        const float4 bv = *(const float4*)(Bp + k0);
        __syncthreads();   // previous iteration's LDS reads complete
        As[lk + 0][lr] = av.x; As[lk + 1][lr] = av.y;
        As[lk + 2][lr] = av.z; As[lk + 3][lr] = av.w;
        Bs[lk + 0][lr] = bv.x; Bs[lk + 1][lr] = bv.y;
        Bs[lk + 2][lr] = bv.z; Bs[lk + 3][lr] = bv.w;
        __syncthreads();
        #pragma unroll
        for (int kk = 0; kk < BK; ++kk) {
            const float4 a = *(const float4*)&As[kk][ty << 2];
            const float4 b = *(const float4*)&Bs[kk][tx << 2];
            const float ar[4] = {a.x, a.y, a.z, a.w};
            const float br[4] = {b.x, b.y, b.z, b.w};
            #pragma unroll
            for (int i = 0; i < 4; ++i)
                #pragma unroll
                for (int j = 0; j < 4; ++j)
                    c[i][j] = fmaf(ar[i], br[j], c[i][j]);
        }
    }

    const int row0 = brow + (ty << 2);
    const int col0 = bcol + (tx << 2);
    const float4 bsv = *(const float4*)(bias + col0);
    #pragma unroll
    for (int i = 0; i < 4; ++i) {
        float4 v;
        v.x = c[i][0] + bsv.x;
        v.y = c[i][1] + bsv.y;
        v.z = c[i][2] + bsv.z;
        v.w = c[i][3] + bsv.w;
        if (RELU) {
            v.x = fmaxf(v.x, 0.f); v.y = fmaxf(v.y, 0.f);
            v.z = fmaxf(v.z, 0.f); v.w = fmaxf(v.w, 0.f);
        }
        *(float4*)(C + (size_t)(row0 + i) * N + col0) = v;
    }
}

// ---------------------------------------------------------------------------
// K4: finalize.
// blocks 0..L-1: masked copy of proto rows (zero where pos_cnt==0).
// blocks L..L+2: anti = sum_l [anti_cnt>0] * OUT[L+l, d] / max(count, 1).
// ---------------------------------------------------------------------------
__global__ __launch_bounds__(256)
void finalize(const float* __restrict__ OUT,      // [2L, D]
              const float* __restrict__ pos_cnt,  // [L]
              float* __restrict__ out)            // [(L+1)*D]
{
    const int blk = blockIdx.x;
    if (blk < L_DIM) {
        const int t = threadIdx.x;
        if (t < 192) {
            const int d0 = t * 4;
            const float keep = (pos_cnt[blk] > 0.f) ? 1.0f : 0.0f;
            float4 v = *(const float4*)(OUT + (size_t)blk * D_DIM + d0);
            v.x *= keep; v.y *= keep; v.z *= keep; v.w *= keep;
            *(float4*)(out + (size_t)blk * D_DIM + d0) = v;
        }
    } else {
        const int d = (blk - L_DIM) * 256 + threadIdx.x;   // 0..767
        float acc = 0.f;
        float wsum = 0.f;
        const float* base = OUT + (size_t)L_DIM * D_DIM + d;
        #pragma unroll 4
        for (int l = 0; l < L_DIM; ++l) {
            const float pc = pos_cnt[l];                    // uniform broadcast
            const float w = ((float)B_DIM - pc > 0.f) ? 1.0f : 0.0f;
            acc = fmaf(w, base[(size_t)l * D_DIM], acc);
            wsum += w;
        }
        out[(size_t)L_DIM * D_DIM + d] = acc / fmaxf(wsum, 1.0f);
    }
}

// ---------------------------------------------------------------------------
extern "C" void kernel_launch(void* const* d_in, const int* in_sizes, int n_in,
                              void* d_out, int out_size, void* d_ws, size_t ws_size,
                              hipStream_t stream) {
    const float* x    = (const float*)d_in[0];
    const int*   mask = (const int*)d_in[1];
    const float* gpt  = (const float*)d_in[2];
    const float* W_h  = (const float*)d_in[3];
    const float* b_h  = (const float*)d_in[4];
    const float* W_p  = (const float*)d_in[5];
    const float* b_p  = (const float*)d_in[6];
    float* out = (float*)d_out;

    float* ws   = (float*)d_ws;
    float* V    = ws;                                   // [2L, D]
    float* Hbuf = V + (size_t)2 * L_DIM * D_DIM;        // [2L, H]
    float* OUT  = Hbuf + (size_t)2 * L_DIM * H_DIM;     // [2L, D]
    float* cnt  = OUT + (size_t)2 * L_DIM * D_DIM;      // [L]

    reduce_build_v<<<L_DIM, 192, 0, stream>>>(x, mask, gpt, V, cnt);

    gemm_atbt<true><<<dim3(H_DIM / BN, 2 * L_DIM / BM), 256, 0, stream>>>(
        V, W_h, b_h, Hbuf, 2 * L_DIM, H_DIM, D_DIM);

    gemm_atbt<false><<<dim3(D_DIM / BN, 2 * L_DIM / BM), 256, 0, stream>>>(
        Hbuf, W_p, b_p, OUT, 2 * L_DIM, D_DIM, H_DIM);

    finalize<<<L_DIM + 3, 256, 0, stream>>>(OUT, cnt, out);
}

// Round 2
// 282.892 us; speedup vs baseline: 1.2086x; 1.2086x over previous
//
#include <hip/hip_runtime.h>

#define L_DIM 1024
#define B_DIM 256
#define D_DIM 768
#define K_DIM 768
#define NT    (K_DIM / 32)

typedef short short8 __attribute__((ext_vector_type(8)));
typedef float floatx4 __attribute__((ext_vector_type(4)));

__device__ __forceinline__ ushort f2bf(float f) {
    union { float f; unsigned u; } v; v.f = f;
    unsigned r = v.u + 0x7FFF + ((v.u >> 16) & 1);   // RNE
    return (ushort)(r >> 16);
}
__device__ __forceinline__ float bf2f(ushort h) {
    union { unsigned u; float f; } v; v.u = ((unsigned)h) << 16;
    return v.f;
}

// ---------------------------------------------------------------------------
// K1: per row l, reduce over B (2 groups of 128 b's, LDS combine), build
//     avg_pos / avg_anti rows and emit them as bf16 hi/lo split for MFMA.
// ---------------------------------------------------------------------------
__global__ __launch_bounds__(384)
void reduce_build_v(const float* __restrict__ x,
                    const int* __restrict__ mask,
                    const float* __restrict__ gpt,
                    ushort* __restrict__ Vhi, ushort* __restrict__ Vlo,
                    float* __restrict__ pos_cnt)
{
    __shared__ float4 posS[192];
    __shared__ float4 totS[192];
    __shared__ float cntS;

    const int l   = blockIdx.x;
    const int tid = threadIdx.x;
    const int g   = tid / 192;       // 0 or 1
    const int t   = tid % 192;
    const int d0  = t * 4;

    float4 pos = make_float4(0.f, 0.f, 0.f, 0.f);
    float4 tot = make_float4(0.f, 0.f, 0.f, 0.f);
    int cnt = 0;

    const size_t bstride = (size_t)L_DIM * D_DIM;
    const float* xp = x + (size_t)l * D_DIM + d0 + (size_t)g * 128 * bstride;
    const int*   mp = mask + l + (size_t)g * 128 * L_DIM;

    #pragma unroll 4
    for (int b = 0; b < 128; ++b) {
        const int m = mp[(size_t)b * L_DIM];
        const float fm = (float)m;
        const float4 v = *(const float4*)(xp + (size_t)b * bstride);
        tot.x += v.x; tot.y += v.y; tot.z += v.z; tot.w += v.w;
        pos.x = fmaf(fm, v.x, pos.x);
        pos.y = fmaf(fm, v.y, pos.y);
        pos.z = fmaf(fm, v.z, pos.z);
        pos.w = fmaf(fm, v.w, pos.w);
        cnt += m;
    }

    if (g == 1) {
        posS[t] = pos; totS[t] = tot;
        if (t == 0) cntS = (float)cnt;
    }
    __syncthreads();
    if (g == 0) {
        const float4 p2 = posS[t];
        const float4 t2 = totS[t];
        pos.x += p2.x; pos.y += p2.y; pos.z += p2.z; pos.w += p2.w;
        tot.x += t2.x; tot.y += t2.y; tot.z += t2.z; tot.w += t2.w;
        const float c = (float)cnt + cntS;

        const float inv_p = 0.5f / fmaxf(c, 1.0f);
        const float inv_a = 0.5f / fmaxf((float)B_DIM - c, 1.0f);

        const float4 g4  = *(const float4*)(gpt + (size_t)l * D_DIM + d0);
        const float4 gl4 = *(const float4*)(gpt + (size_t)L_DIM * D_DIM + d0);

        float vp[4], va[4];
        vp[0] = pos.x * inv_p + 0.5f * g4.x;
        vp[1] = pos.y * inv_p + 0.5f * g4.y;
        vp[2] = pos.z * inv_p + 0.5f * g4.z;
        vp[3] = pos.w * inv_p + 0.5f * g4.w;
        va[0] = (tot.x - pos.x) * inv_a + 0.5f * gl4.x;
        va[1] = (tot.y - pos.y) * inv_a + 0.5f * gl4.y;
        va[2] = (tot.z - pos.z) * inv_a + 0.5f * gl4.z;
        va[3] = (tot.w - pos.w) * inv_a + 0.5f * gl4.w;

        ushort4 ph, pl, ah, al;
        ph.x = f2bf(vp[0]); pl.x = f2bf(vp[0] - bf2f(ph.x));
        ph.y = f2bf(vp[1]); pl.y = f2bf(vp[1] - bf2f(ph.y));
        ph.z = f2bf(vp[2]); pl.z = f2bf(vp[2] - bf2f(ph.z));
        ph.w = f2bf(vp[3]); pl.w = f2bf(vp[3] - bf2f(ph.w));
        ah.x = f2bf(va[0]); al.x = f2bf(va[0] - bf2f(ah.x));
        ah.y = f2bf(va[1]); al.y = f2bf(va[1] - bf2f(ah.y));
        ah.z = f2bf(va[2]); al.z = f2bf(va[2] - bf2f(ah.z));
        ah.w = f2bf(va[3]); al.w = f2bf(va[3] - bf2f(ah.w));

        const size_t r0 = (size_t)l * D_DIM + d0;
        const size_t r1 = (size_t)(L_DIM + l) * D_DIM + d0;
        *(ushort4*)(Vhi + r0) = ph;  *(ushort4*)(Vlo + r0) = pl;
        *(ushort4*)(Vhi + r1) = ah;  *(ushort4*)(Vlo + r1) = al;

        if (t == 0) pos_cnt[l] = c;
    }
}

// ---------------------------------------------------------------------------
// K2: cast W_h and W_p (f32 [768*768] each) to bf16 hi/lo.
// ---------------------------------------------------------------------------
__global__ __launch_bounds__(256)
void cast_w(const float* __restrict__ Wh, const float* __restrict__ Wp,
            ushort* __restrict__ WhHi, ushort* __restrict__ WhLo,
            ushort* __restrict__ WpHi, ushort* __restrict__ WpLo)
{
    const int n = 768 * 768;
    int i = (blockIdx.x * 256 + threadIdx.x) * 4;
    const float* src; ushort* dh; ushort* dl; int j;
    if (i < n) { src = Wh; dh = WhHi; dl = WhLo; j = i; }
    else       { src = Wp; dh = WpHi; dl = WpLo; j = i - n; }
    const float4 v = *(const float4*)(src + j);
    ushort4 hi, lo;
    hi.x = f2bf(v.x); lo.x = f2bf(v.x - bf2f(hi.x));
    hi.y = f2bf(v.y); lo.y = f2bf(v.y - bf2f(hi.y));
    hi.z = f2bf(v.z); lo.z = f2bf(v.z - bf2f(hi.z));
    hi.w = f2bf(v.w); lo.w = f2bf(v.w - bf2f(hi.w));
    *(ushort4*)(dh + j) = hi;
    *(ushort4*)(dl + j) = lo;
}

// ---------------------------------------------------------------------------
// Split-bf16 MFMA GEMM: C[M,2048][N,768] = A[M,K] @ B[N,K]^T (+bias).
// 64x64 block tile, 4 waves of 32x32 (2x2 frags of 16x16x32), BK=32.
// 3-term split: Ah*Bh + Al*Bh + Ah*Bl  (fp32-level accuracy).
// MODE 0: ReLU, emit bf16 hi/lo (H buffers).
// MODE 1: rows<1024 -> masked write to d_out; rows>=1024 -> Anti ws buffer.
// ---------------------------------------------------------------------------
template<int MODE>
__global__ __launch_bounds__(256)
void gemm_split(const ushort* __restrict__ Ahi, const ushort* __restrict__ Alo,
                const ushort* __restrict__ Bhi, const ushort* __restrict__ Blo,
                const float* __restrict__ bias,
                ushort* __restrict__ OutHi, ushort* __restrict__ OutLo,
                float* __restrict__ OutF, float* __restrict__ Anti,
                const float* __restrict__ cnt)
{
    __shared__ ushort As_hi[64 * 32];
    __shared__ ushort As_lo[64 * 32];
    __shared__ ushort Bs_hi[64 * 32];
    __shared__ ushort Bs_lo[64 * 32];

    const int tid  = threadIdx.x;
    const int lane = tid & 63;
    const int wid  = tid >> 6;
    const int brow = blockIdx.y * 64;
    const int bcol = blockIdx.x * 64;
    const int wr   = (wid >> 1) * 32;
    const int wc   = (wid & 1) * 32;

    const int srow = tid >> 2;          // 0..63
    const int sk   = (tid & 3) * 8;     // 0,8,16,24

    const ushort* pAh = Ahi + (size_t)(brow + srow) * K_DIM + sk;
    const ushort* pAl = Alo + (size_t)(brow + srow) * K_DIM + sk;
    const ushort* pBh = Bhi + (size_t)(bcol + srow) * K_DIM + sk;
    const ushort* pBl = Blo + (size_t)(bcol + srow) * K_DIM + sk;

    floatx4 acc[2][2] = {};

    uint4 rAh = *(const uint4*)pAh;
    uint4 rAl = *(const uint4*)pAl;
    uint4 rBh = *(const uint4*)pBh;
    uint4 rBl = *(const uint4*)pBl;

    const int ldst = tid * 8;           // ushort offset (16B per thread)
    const int fA0 = (wr +  0 + (lane & 15)) * 32 + (lane >> 4) * 8;
    const int fA1 = (wr + 16 + (lane & 15)) * 32 + (lane >> 4) * 8;
    const int fB0 = (wc +  0 + (lane & 15)) * 32 + (lane >> 4) * 8;
    const int fB1 = (wc + 16 + (lane & 15)) * 32 + (lane >> 4) * 8;

    for (int t = 0; t < NT; ++t) {
        __syncthreads();
        *(uint4*)&As_hi[ldst] = rAh;
        *(uint4*)&As_lo[ldst] = rAl;
        *(uint4*)&Bs_hi[ldst] = rBh;
        *(uint4*)&Bs_lo[ldst] = rBl;
        __syncthreads();
        if (t + 1 < NT) {
            const int ko = (t + 1) * 32;
            rAh = *(const uint4*)(pAh + ko);
            rAl = *(const uint4*)(pAl + ko);
            rBh = *(const uint4*)(pBh + ko);
            rBl = *(const uint4*)(pBl + ko);
        }
        short8 ah[2], al[2], bh[2], bl[2];
        ah[0] = *(short8*)&As_hi[fA0];  ah[1] = *(short8*)&As_hi[fA1];
        al[0] = *(short8*)&As_lo[fA0];  al[1] = *(short8*)&As_lo[fA1];
        bh[0] = *(short8*)&Bs_hi[fB0];  bh[1] = *(short8*)&Bs_hi[fB1];
        bl[0] = *(short8*)&Bs_lo[fB0];  bl[1] = *(short8*)&Bs_lo[fB1];
        #pragma unroll
        for (int mi = 0; mi < 2; ++mi)
            #pragma unroll
            for (int ni = 0; ni < 2; ++ni) {
                acc[mi][ni] = __builtin_amdgcn_mfma_f32_16x16x32_bf16(ah[mi], bh[ni], acc[mi][ni], 0, 0, 0);
                acc[mi][ni] = __builtin_amdgcn_mfma_f32_16x16x32_bf16(al[mi], bh[ni], acc[mi][ni], 0, 0, 0);
                acc[mi][ni] = __builtin_amdgcn_mfma_f32_16x16x32_bf16(ah[mi], bl[ni], acc[mi][ni], 0, 0, 0);
            }
    }

    #pragma unroll
    for (int mi = 0; mi < 2; ++mi) {
        #pragma unroll
        for (int ni = 0; ni < 2; ++ni) {
            const int col   = bcol + wc + ni * 16 + (lane & 15);
            const int rbase = brow + wr + mi * 16 + ((lane >> 4) << 2);
            const float bv = bias[col];
            #pragma unroll
            for (int r = 0; r < 4; ++r) {
                const float v = acc[mi][ni][r] + bv;
                const int row = rbase + r;
                if (MODE == 0) {
                    const float h = fmaxf(v, 0.f);
                    const ushort hh = f2bf(h);
                    OutHi[(size_t)row * D_DIM + col] = hh;
                    OutLo[(size_t)row * D_DIM + col] = f2bf(h - bf2f(hh));
                } else {
                    if (row < L_DIM) {
                        OutF[(size_t)row * D_DIM + col] = (cnt[row] > 0.f) ? v : 0.f;
                    } else {
                        Anti[(size_t)(row - L_DIM) * D_DIM + col] = v;
                    }
                }
            }
        }
    }
}

// ---------------------------------------------------------------------------
// K5: anti row = sum_l [anti_cnt>0] * Anti[l,d] / max(count,1)
// ---------------------------------------------------------------------------
__global__ __launch_bounds__(256)
void finalize_anti(const float* __restrict__ Anti,
                   const float* __restrict__ cnt,
                   float* __restrict__ out)
{
    const int d = blockIdx.x * 256 + threadIdx.x;   // 0..767
    float acc = 0.f, wsum = 0.f;
    #pragma unroll 4
    for (int l = 0; l < L_DIM; ++l) {
        const float w = ((float)B_DIM - cnt[l] > 0.f) ? 1.0f : 0.0f;
        acc = fmaf(w, Anti[(size_t)l * D_DIM + d], acc);
        wsum += w;
    }
    out[(size_t)L_DIM * D_DIM + d] = acc / fmaxf(wsum, 1.0f);
}

// ---------------------------------------------------------------------------
extern "C" void kernel_launch(void* const* d_in, const int* in_sizes, int n_in,
                              void* d_out, int out_size, void* d_ws, size_t ws_size,
                              hipStream_t stream) {
    const float* x    = (const float*)d_in[0];
    const int*   mask = (const int*)d_in[1];
    const float* gpt  = (const float*)d_in[2];
    const float* W_h  = (const float*)d_in[3];
    const float* b_h  = (const float*)d_in[4];
    const float* W_p  = (const float*)d_in[5];
    const float* b_p  = (const float*)d_in[6];
    float* out = (float*)d_out;

    char* p = (char*)d_ws;
    ushort* Vhi  = (ushort*)p; p += (size_t)2 * L_DIM * D_DIM * 2;
    ushort* Vlo  = (ushort*)p; p += (size_t)2 * L_DIM * D_DIM * 2;
    ushort* Hhi  = (ushort*)p; p += (size_t)2 * L_DIM * D_DIM * 2;
    ushort* Hlo  = (ushort*)p; p += (size_t)2 * L_DIM * D_DIM * 2;
    ushort* WhHi = (ushort*)p; p += (size_t)768 * 768 * 2;
    ushort* WhLo = (ushort*)p; p += (size_t)768 * 768 * 2;
    ushort* WpHi = (ushort*)p; p += (size_t)768 * 768 * 2;
    ushort* WpLo = (ushort*)p; p += (size_t)768 * 768 * 2;
    float*  Anti = (float*)p;  p += (size_t)L_DIM * D_DIM * 4;
    float*  cnt  = (float*)p;

    reduce_build_v<<<L_DIM, 384, 0, stream>>>(x, mask, gpt, Vhi, Vlo, cnt);

    cast_w<<<(768 * 768 * 2 / 4) / 256, 256, 0, stream>>>(W_h, W_p, WhHi, WhLo, WpHi, WpLo);

    dim3 ggrid(D_DIM / 64, 2 * L_DIM / 64);
    gemm_split<0><<<ggrid, 256, 0, stream>>>(Vhi, Vlo, WhHi, WhLo, b_h,
                                             Hhi, Hlo, nullptr, nullptr, nullptr);
    gemm_split<1><<<ggrid, 256, 0, stream>>>(Hhi, Hlo, WpHi, WpLo, b_p,
                                             nullptr, nullptr, out, Anti, cnt);

    finalize_anti<<<3, 256, 0, stream>>>(Anti, cnt, out);
}

// Round 3
// 221.894 us; speedup vs baseline: 1.5409x; 1.2749x over previous
//
#include <hip/hip_runtime.h>

#define L_DIM 1024
#define B_DIM 256
#define D_DIM 768
#define K_DIM 768
#define NT    (K_DIM / 32)

typedef short short8 __attribute__((ext_vector_type(8)));
typedef float floatx4 __attribute__((ext_vector_type(4)));

__device__ __forceinline__ ushort f2bf(float f) {
    union { float f; unsigned u; } v; v.f = f;
    unsigned r = v.u + 0x7FFF + ((v.u >> 16) & 1);   // RNE
    return (ushort)(r >> 16);
}
__device__ __forceinline__ float bf2f(ushort h) {
    union { unsigned u; float f; } v; v.u = ((unsigned)h) << 16;
    return v.f;
}
__device__ __forceinline__ unsigned pack2(ushort a, ushort b) {
    return (unsigned)a | ((unsigned)b << 16);
}

// ---------------------------------------------------------------------------
// K1: per row l, reduce over B (2 groups of 128 b's, LDS combine), build
//     avg_pos / avg_anti rows, emit as bf16 hi/lo split for MFMA.
// ---------------------------------------------------------------------------
__global__ __launch_bounds__(384)
void reduce_build_v(const float* __restrict__ x,
                    const int* __restrict__ mask,
                    const float* __restrict__ gpt,
                    ushort* __restrict__ Vhi, ushort* __restrict__ Vlo,
                    float* __restrict__ pos_cnt)
{
    __shared__ float4 posS[192];
    __shared__ float4 totS[192];
    __shared__ float cntS;

    const int l   = blockIdx.x;
    const int tid = threadIdx.x;
    const int g   = tid / 192;       // 0 or 1
    const int t   = tid % 192;
    const int d0  = t * 4;

    float4 pos = make_float4(0.f, 0.f, 0.f, 0.f);
    float4 tot = make_float4(0.f, 0.f, 0.f, 0.f);
    int cnt = 0;

    const size_t bstride = (size_t)L_DIM * D_DIM;
    const float* xp = x + (size_t)l * D_DIM + d0 + (size_t)g * 128 * bstride;
    const int*   mp = mask + l + (size_t)g * 128 * L_DIM;

    #pragma unroll 8
    for (int b = 0; b < 128; ++b) {
        const int m = mp[(size_t)b * L_DIM];
        const float fm = (float)m;
        const float4 v = *(const float4*)(xp + (size_t)b * bstride);
        tot.x += v.x; tot.y += v.y; tot.z += v.z; tot.w += v.w;
        pos.x = fmaf(fm, v.x, pos.x);
        pos.y = fmaf(fm, v.y, pos.y);
        pos.z = fmaf(fm, v.z, pos.z);
        pos.w = fmaf(fm, v.w, pos.w);
        cnt += m;
    }

    if (g == 1) {
        posS[t] = pos; totS[t] = tot;
        if (t == 0) cntS = (float)cnt;
    }
    __syncthreads();
    if (g == 0) {
        const float4 p2 = posS[t];
        const float4 t2 = totS[t];
        pos.x += p2.x; pos.y += p2.y; pos.z += p2.z; pos.w += p2.w;
        tot.x += t2.x; tot.y += t2.y; tot.z += t2.z; tot.w += t2.w;
        const float c = (float)cnt + cntS;

        const float inv_p = 0.5f / fmaxf(c, 1.0f);
        const float inv_a = 0.5f / fmaxf((float)B_DIM - c, 1.0f);

        const float4 g4  = *(const float4*)(gpt + (size_t)l * D_DIM + d0);
        const float4 gl4 = *(const float4*)(gpt + (size_t)L_DIM * D_DIM + d0);

        float vp[4], va[4];
        vp[0] = pos.x * inv_p + 0.5f * g4.x;
        vp[1] = pos.y * inv_p + 0.5f * g4.y;
        vp[2] = pos.z * inv_p + 0.5f * g4.z;
        vp[3] = pos.w * inv_p + 0.5f * g4.w;
        va[0] = (tot.x - pos.x) * inv_a + 0.5f * gl4.x;
        va[1] = (tot.y - pos.y) * inv_a + 0.5f * gl4.y;
        va[2] = (tot.z - pos.z) * inv_a + 0.5f * gl4.z;
        va[3] = (tot.w - pos.w) * inv_a + 0.5f * gl4.w;

        ushort4 ph, pl, ah, al;
        ph.x = f2bf(vp[0]); pl.x = f2bf(vp[0] - bf2f(ph.x));
        ph.y = f2bf(vp[1]); pl.y = f2bf(vp[1] - bf2f(ph.y));
        ph.z = f2bf(vp[2]); pl.z = f2bf(vp[2] - bf2f(ph.z));
        ph.w = f2bf(vp[3]); pl.w = f2bf(vp[3] - bf2f(ph.w));
        ah.x = f2bf(va[0]); al.x = f2bf(va[0] - bf2f(ah.x));
        ah.y = f2bf(va[1]); al.y = f2bf(va[1] - bf2f(ah.y));
        ah.z = f2bf(va[2]); al.z = f2bf(va[2] - bf2f(ah.z));
        ah.w = f2bf(va[3]); al.w = f2bf(va[3] - bf2f(ah.w));

        const size_t r0 = (size_t)l * D_DIM + d0;
        const size_t r1 = (size_t)(L_DIM + l) * D_DIM + d0;
        *(ushort4*)(Vhi + r0) = ph;  *(ushort4*)(Vlo + r0) = pl;
        *(ushort4*)(Vhi + r1) = ah;  *(ushort4*)(Vlo + r1) = al;

        if (t == 0) pos_cnt[l] = c;
    }
}

// ---------------------------------------------------------------------------
// Split-bf16 MFMA GEMM: C[2048, 768] = A[M,K](bf16 hi/lo) @ B[N,K]^T(f32) + bias.
// B is converted to bf16 hi/lo in-register during LDS staging.
// 64x64 tile, 4 waves of 32x32 (2x2 frags of 16x16x32), BK=32.
// 3-term: Ah*Bh + Al*Bh + Ah*Bl.
// MODE 0: ReLU, emit bf16 hi/lo (H buffers).
// MODE 1: rows<1024 -> masked write to d_out;
//         rows>=1024 -> per-block weighted column sums into Partial[16][768].
// ---------------------------------------------------------------------------
template<int MODE>
__global__ __launch_bounds__(256)
void gemm_split(const ushort* __restrict__ Ahi, const ushort* __restrict__ Alo,
                const float* __restrict__ Bf, const float* __restrict__ bias,
                ushort* __restrict__ OutHi, ushort* __restrict__ OutLo,
                float* __restrict__ OutF, float* __restrict__ Partial,
                const float* __restrict__ cnt)
{
    __shared__ ushort As_hi[64 * 32];
    __shared__ ushort As_lo[64 * 32];
    __shared__ ushort Bs_hi[64 * 32];
    __shared__ ushort Bs_lo[64 * 32];
    __shared__ float  colsum[4][32];

    const int tid  = threadIdx.x;
    const int lane = tid & 63;
    const int wid  = tid >> 6;
    const int brow = blockIdx.y * 64;
    const int bcol = blockIdx.x * 64;
    const int wr   = (wid >> 1) * 32;
    const int wc   = (wid & 1) * 32;

    const int srow = tid >> 2;          // 0..63
    const int sk   = (tid & 3) * 8;     // 0,8,16,24

    const ushort* pAh = Ahi + (size_t)(brow + srow) * K_DIM + sk;
    const ushort* pAl = Alo + (size_t)(brow + srow) * K_DIM + sk;
    const float*  pBf = Bf  + (size_t)(bcol + srow) * K_DIM + sk;

    floatx4 acc[2][2] = {};

    uint4  rAh = *(const uint4*)pAh;
    uint4  rAl = *(const uint4*)pAl;
    float4 rB0 = *(const float4*)pBf;
    float4 rB1 = *(const float4*)(pBf + 4);

    const int ldst = tid * 8;           // ushort offset (16B per thread)
    const int fA0 = (wr +  0 + (lane & 15)) * 32 + (lane >> 4) * 8;
    const int fA1 = (wr + 16 + (lane & 15)) * 32 + (lane >> 4) * 8;
    const int fB0 = (wc +  0 + (lane & 15)) * 32 + (lane >> 4) * 8;
    const int fB1 = (wc + 16 + (lane & 15)) * 32 + (lane >> 4) * 8;

    for (int t = 0; t < NT; ++t) {
        __syncthreads();
        {
            const float fb[8] = {rB0.x, rB0.y, rB0.z, rB0.w,
                                 rB1.x, rB1.y, rB1.z, rB1.w};
            ushort hb[8], lb[8];
            #pragma unroll
            for (int j = 0; j < 8; ++j) {
                hb[j] = f2bf(fb[j]);
                lb[j] = f2bf(fb[j] - bf2f(hb[j]));
            }
            uint4 uh, ul;
            uh.x = pack2(hb[0], hb[1]); uh.y = pack2(hb[2], hb[3]);
            uh.z = pack2(hb[4], hb[5]); uh.w = pack2(hb[6], hb[7]);
            ul.x = pack2(lb[0], lb[1]); ul.y = pack2(lb[2], lb[3]);
            ul.z = pack2(lb[4], lb[5]); ul.w = pack2(lb[6], lb[7]);
            *(uint4*)&As_hi[ldst] = rAh;
            *(uint4*)&As_lo[ldst] = rAl;
            *(uint4*)&Bs_hi[ldst] = uh;
            *(uint4*)&Bs_lo[ldst] = ul;
        }
        __syncthreads();
        if (t + 1 < NT) {
            const int ko = (t + 1) * 32;
            rAh = *(const uint4*)(pAh + ko);
            rAl = *(const uint4*)(pAl + ko);
            rB0 = *(const float4*)(pBf + ko);
            rB1 = *(const float4*)(pBf + ko + 4);
        }
        short8 ah[2], al[2], bh[2], bl[2];
        ah[0] = *(short8*)&As_hi[fA0];  ah[1] = *(short8*)&As_hi[fA1];
        al[0] = *(short8*)&As_lo[fA0];  al[1] = *(short8*)&As_lo[fA1];
        bh[0] = *(short8*)&Bs_hi[fB0];  bh[1] = *(short8*)&Bs_hi[fB1];
        bl[0] = *(short8*)&Bs_lo[fB0];  bl[1] = *(short8*)&Bs_lo[fB1];
        #pragma unroll
        for (int mi = 0; mi < 2; ++mi)
            #pragma unroll
            for (int ni = 0; ni < 2; ++ni) {
                acc[mi][ni] = __builtin_amdgcn_mfma_f32_16x16x32_bf16(ah[mi], bh[ni], acc[mi][ni], 0, 0, 0);
                acc[mi][ni] = __builtin_amdgcn_mfma_f32_16x16x32_bf16(al[mi], bh[ni], acc[mi][ni], 0, 0, 0);
                acc[mi][ni] = __builtin_amdgcn_mfma_f32_16x16x32_bf16(ah[mi], bl[ni], acc[mi][ni], 0, 0, 0);
            }
    }

    if (MODE == 0 || brow < L_DIM) {
        #pragma unroll
        for (int mi = 0; mi < 2; ++mi) {
            #pragma unroll
            for (int ni = 0; ni < 2; ++ni) {
                const int col   = bcol + wc + ni * 16 + (lane & 15);
                const int rbase = brow + wr + mi * 16 + ((lane >> 4) << 2);
                const float bv = bias[col];
                #pragma unroll
                for (int r = 0; r < 4; ++r) {
                    const float v = acc[mi][ni][r] + bv;
                    const int row = rbase + r;
                    if (MODE == 0) {
                        const float h = fmaxf(v, 0.f);
                        const ushort hh = f2bf(h);
                        OutHi[(size_t)row * D_DIM + col] = hh;
                        OutLo[(size_t)row * D_DIM + col] = f2bf(h - bf2f(hh));
                    } else {
                        OutF[(size_t)row * D_DIM + col] = (cnt[row] > 0.f) ? v : 0.f;
                    }
                }
            }
        }
    } else {
        // anti half: weighted column sums over this block's 64 rows
        float s[2] = {0.f, 0.f};
        #pragma unroll
        for (int mi = 0; mi < 2; ++mi) {
            const int rbase = brow + wr + mi * 16 + ((lane >> 4) << 2);
            #pragma unroll
            for (int r = 0; r < 4; ++r) {
                const float w = (cnt[rbase + r - L_DIM] < 255.5f) ? 1.0f : 0.0f;
                #pragma unroll
                for (int ni = 0; ni < 2; ++ni) {
                    const int col = bcol + wc + ni * 16 + (lane & 15);
                    s[ni] = fmaf(w, acc[mi][ni][r] + bias[col], s[ni]);
                }
            }
        }
        #pragma unroll
        for (int ni = 0; ni < 2; ++ni) {
            s[ni] += __shfl_down(s[ni], 32);
            s[ni] += __shfl_down(s[ni], 16);
            if (lane < 16) colsum[wid][ni * 16 + lane] = s[ni];
        }
        __syncthreads();
        if (tid < 64) {
            const float v = (tid < 32)
                ? colsum[0][tid] + colsum[2][tid]
                : colsum[1][tid - 32] + colsum[3][tid - 32];
            Partial[(size_t)(blockIdx.y - 16) * D_DIM + bcol + tid] = v;
        }
    }
}

// ---------------------------------------------------------------------------
// K4: anti row = (sum of 16 partials per column) / max(wsum, 1)
// ---------------------------------------------------------------------------
__global__ __launch_bounds__(256)
void finalize_anti(const float* __restrict__ Partial,
                   const float* __restrict__ cnt,
                   float* __restrict__ out)
{
    const int d = blockIdx.x * 256 + threadIdx.x;   // 0..767
    float s = 0.f;
    #pragma unroll
    for (int p = 0; p < 16; ++p) s += Partial[(size_t)p * D_DIM + d];
    float wsum = 0.f;
    #pragma unroll 8
    for (int l = 0; l < L_DIM; ++l) wsum += (cnt[l] < 255.5f) ? 1.0f : 0.0f;
    out[(size_t)L_DIM * D_DIM + d] = s / fmaxf(wsum, 1.0f);
}

// ---------------------------------------------------------------------------
extern "C" void kernel_launch(void* const* d_in, const int* in_sizes, int n_in,
                              void* d_out, int out_size, void* d_ws, size_t ws_size,
                              hipStream_t stream) {
    const float* x    = (const float*)d_in[0];
    const int*   mask = (const int*)d_in[1];
    const float* gpt  = (const float*)d_in[2];
    const float* W_h  = (const float*)d_in[3];
    const float* b_h  = (const float*)d_in[4];
    const float* W_p  = (const float*)d_in[5];
    const float* b_p  = (const float*)d_in[6];
    float* out = (float*)d_out;

    char* p = (char*)d_ws;
    ushort* Vhi  = (ushort*)p; p += (size_t)2 * L_DIM * D_DIM * 2;
    ushort* Vlo  = (ushort*)p; p += (size_t)2 * L_DIM * D_DIM * 2;
    ushort* Hhi  = (ushort*)p; p += (size_t)2 * L_DIM * D_DIM * 2;
    ushort* Hlo  = (ushort*)p; p += (size_t)2 * L_DIM * D_DIM * 2;
    float*  Part = (float*)p;  p += (size_t)16 * D_DIM * 4;
    float*  cnt  = (float*)p;

    reduce_build_v<<<L_DIM, 384, 0, stream>>>(x, mask, gpt, Vhi, Vlo, cnt);

    dim3 ggrid(D_DIM / 64, 2 * L_DIM / 64);
    gemm_split<0><<<ggrid, 256, 0, stream>>>(Vhi, Vlo, W_h, b_h,
                                             Hhi, Hlo, nullptr, nullptr, nullptr);
    gemm_split<1><<<ggrid, 256, 0, stream>>>(Hhi, Hlo, W_p, b_p,
                                             nullptr, nullptr, out, Part, cnt);

    finalize_anti<<<3, 256, 0, stream>>>(Part, cnt, out);
}

// Round 4
// 206.457 us; speedup vs baseline: 1.6561x; 1.0748x over previous
//
#include <hip/hip_runtime.h>

#define L_DIM 1024
#define B_DIM 256
#define D_DIM 768
#define K_DIM 768
#define NT    (K_DIM / 32)

typedef short short8 __attribute__((ext_vector_type(8)));
typedef float floatx4 __attribute__((ext_vector_type(4)));

__device__ __forceinline__ ushort f2bf(float f) {
    union { float f; unsigned u; } v; v.f = f;
    unsigned r = v.u + 0x7FFF + ((v.u >> 16) & 1);   // RNE
    return (ushort)(r >> 16);
}
__device__ __forceinline__ float bf2f(ushort h) {
    union { unsigned u; float f; } v; v.u = ((unsigned)h) << 16;
    return v.f;
}

__device__ __forceinline__ void gl16(const ushort* g, ushort* l) {
    __builtin_amdgcn_global_load_lds(
        (const __attribute__((address_space(1))) unsigned int*)g,
        (__attribute__((address_space(3))) unsigned int*)l, 16, 0, 0);
}

// ---------------------------------------------------------------------------
// K1: 256 blocks x 768 threads; block owns 4 consecutive l rows.
// Per b-step the block reads 12KB contiguous. Each thread owns one
// (row, d-quad) across ALL 256 b's -> no cross-thread combine.
// Emits avg_pos/avg_anti as bf16 hi/lo.
// ---------------------------------------------------------------------------
__global__ __launch_bounds__(768)
void reduce_build_v(const float* __restrict__ x,
                    const int* __restrict__ mask,
                    const float* __restrict__ gpt,
                    ushort* __restrict__ Vhi, ushort* __restrict__ Vlo,
                    float* __restrict__ pos_cnt)
{
    __shared__ int mS[256][4];

    const int l0  = blockIdx.x * 4;
    const int tid = threadIdx.x;

    if (tid < 256)
        *(int4*)&mS[tid][0] = *(const int4*)(mask + (size_t)tid * L_DIM + l0);
    __syncthreads();

    const int row = tid / 192;       // 0..3
    const int t   = tid % 192;
    const int d0  = t * 4;
    const int l   = l0 + row;

    const size_t bstride = (size_t)L_DIM * D_DIM;
    const float* xp = x + (size_t)l * D_DIM + d0;

    float4 pos = make_float4(0.f, 0.f, 0.f, 0.f);
    float4 tot = make_float4(0.f, 0.f, 0.f, 0.f);
    float cnt = 0.f;

    #pragma unroll 8
    for (int b = 0; b < B_DIM; ++b) {
        const float4 v = *(const float4*)(xp + (size_t)b * bstride);
        const float fm = (float)mS[b][row];
        tot.x += v.x; tot.y += v.y; tot.z += v.z; tot.w += v.w;
        pos.x = fmaf(fm, v.x, pos.x);
        pos.y = fmaf(fm, v.y, pos.y);
        pos.z = fmaf(fm, v.z, pos.z);
        pos.w = fmaf(fm, v.w, pos.w);
        cnt += fm;
    }

    const float inv_p = 0.5f / fmaxf(cnt, 1.0f);
    const float inv_a = 0.5f / fmaxf((float)B_DIM - cnt, 1.0f);

    const float4 g4  = *(const float4*)(gpt + (size_t)l * D_DIM + d0);
    const float4 gl4 = *(const float4*)(gpt + (size_t)L_DIM * D_DIM + d0);

    float vp[4], va[4];
    vp[0] = pos.x * inv_p + 0.5f * g4.x;
    vp[1] = pos.y * inv_p + 0.5f * g4.y;
    vp[2] = pos.z * inv_p + 0.5f * g4.z;
    vp[3] = pos.w * inv_p + 0.5f * g4.w;
    va[0] = (tot.x - pos.x) * inv_a + 0.5f * gl4.x;
    va[1] = (tot.y - pos.y) * inv_a + 0.5f * gl4.y;
    va[2] = (tot.z - pos.z) * inv_a + 0.5f * gl4.z;
    va[3] = (tot.w - pos.w) * inv_a + 0.5f * gl4.w;

    ushort4 ph, pl, ah, al;
    ph.x = f2bf(vp[0]); pl.x = f2bf(vp[0] - bf2f(ph.x));
    ph.y = f2bf(vp[1]); pl.y = f2bf(vp[1] - bf2f(ph.y));
    ph.z = f2bf(vp[2]); pl.z = f2bf(vp[2] - bf2f(ph.z));
    ph.w = f2bf(vp[3]); pl.w = f2bf(vp[3] - bf2f(ph.w));
    ah.x = f2bf(va[0]); al.x = f2bf(va[0] - bf2f(ah.x));
    ah.y = f2bf(va[1]); al.y = f2bf(va[1] - bf2f(ah.y));
    ah.z = f2bf(va[2]); al.z = f2bf(va[2] - bf2f(ah.z));
    ah.w = f2bf(va[3]); al.w = f2bf(va[3] - bf2f(ah.w));

    const size_t r0 = (size_t)l * D_DIM + d0;
    const size_t r1 = (size_t)(L_DIM + l) * D_DIM + d0;
    *(ushort4*)(Vhi + r0) = ph;  *(ushort4*)(Vlo + r0) = pl;
    *(ushort4*)(Vhi + r1) = ah;  *(ushort4*)(Vlo + r1) = al;

    if (t == 0) pos_cnt[l] = cnt;
}

// ---------------------------------------------------------------------------
// K0: cast W_h and W_p (f32 [768*768] each) to bf16 hi/lo.
// ---------------------------------------------------------------------------
__global__ __launch_bounds__(256)
void cast_w(const float* __restrict__ Wh, const float* __restrict__ Wp,
            ushort* __restrict__ WhHi, ushort* __restrict__ WhLo,
            ushort* __restrict__ WpHi, ushort* __restrict__ WpLo)
{
    const int n = 768 * 768;
    int i = (blockIdx.x * 256 + threadIdx.x) * 4;
    const float* src; ushort* dh; ushort* dl; int j;
    if (i < n) { src = Wh; dh = WhHi; dl = WhLo; j = i; }
    else       { src = Wp; dh = WpHi; dl = WpLo; j = i - n; }
    const float4 v = *(const float4*)(src + j);
    ushort4 hi, lo;
    hi.x = f2bf(v.x); lo.x = f2bf(v.x - bf2f(hi.x));
    hi.y = f2bf(v.y); lo.y = f2bf(v.y - bf2f(hi.y));
    hi.z = f2bf(v.z); lo.z = f2bf(v.z - bf2f(hi.z));
    hi.w = f2bf(v.w); lo.w = f2bf(v.w - bf2f(hi.w));
    *(ushort4*)(dh + j) = hi;
    *(ushort4*)(dl + j) = lo;
}

// ---------------------------------------------------------------------------
// Split-bf16 MFMA GEMM with global_load_lds staging + LDS double-buffer.
// C[2048,768] = A[M,K] @ B[N,K]^T + bias; 64x64 tile, 4 waves (2x2 of 16x16x32).
// 3-term: Ah*Bh + Al*Bh + Ah*Bl.
// MODE 0: ReLU, emit bf16 hi/lo. MODE 1: proto rows -> masked d_out,
// anti rows -> per-block weighted column sums into Partial.
// ---------------------------------------------------------------------------
template<int MODE>
__global__ __launch_bounds__(256)
void gemm_split(const ushort* __restrict__ Ahi, const ushort* __restrict__ Alo,
                const ushort* __restrict__ Bhi, const ushort* __restrict__ Blo,
                const float* __restrict__ bias,
                ushort* __restrict__ OutHi, ushort* __restrict__ OutLo,
                float* __restrict__ OutF, float* __restrict__ Partial,
                const float* __restrict__ cnt)
{
    __shared__ ushort lds[2][4][64 * 32];
    __shared__ float  colsum[4][32];

    const int tid  = threadIdx.x;
    const int lane = tid & 63;
    const int wid  = tid >> 6;
    const int brow = blockIdx.y * 64;
    const int bcol = blockIdx.x * 64;
    const int wr   = (wid >> 1) * 32;
    const int wc   = (wid & 1) * 32;

    const int srow = tid >> 2;          // 0..63
    const int sk   = (tid & 3) * 8;     // 0,8,16,24

    const ushort* pAh = Ahi + (size_t)(brow + srow) * K_DIM + sk;
    const ushort* pAl = Alo + (size_t)(brow + srow) * K_DIM + sk;
    const ushort* pBh = Bhi + (size_t)(bcol + srow) * K_DIM + sk;
    const ushort* pBl = Blo + (size_t)(bcol + srow) * K_DIM + sk;

    const int ldst = tid * 8;           // ushort offset within buffer
    const int fA0 = (wr +  0 + (lane & 15)) * 32 + (lane >> 4) * 8;
    const int fA1 = (wr + 16 + (lane & 15)) * 32 + (lane >> 4) * 8;
    const int fB0 = (wc +  0 + (lane & 15)) * 32 + (lane >> 4) * 8;
    const int fB1 = (wc + 16 + (lane & 15)) * 32 + (lane >> 4) * 8;

    floatx4 acc[2][2] = {};

    // prologue stage tile 0 into buffer 0
    gl16(pAh, &lds[0][0][ldst]);
    gl16(pAl, &lds[0][1][ldst]);
    gl16(pBh, &lds[0][2][ldst]);
    gl16(pBl, &lds[0][3][ldst]);
    __syncthreads();

    for (int t = 0; t < NT; ++t) {
        const int cur = t & 1;
        if (t + 1 < NT) {
            const int ko = (t + 1) * 32;
            const int nxt = cur ^ 1;
            gl16(pAh + ko, &lds[nxt][0][ldst]);
            gl16(pAl + ko, &lds[nxt][1][ldst]);
            gl16(pBh + ko, &lds[nxt][2][ldst]);
            gl16(pBl + ko, &lds[nxt][3][ldst]);
        }
        short8 ah[2], al[2], bh[2], bl[2];
        ah[0] = *(short8*)&lds[cur][0][fA0];  ah[1] = *(short8*)&lds[cur][0][fA1];
        al[0] = *(short8*)&lds[cur][1][fA0];  al[1] = *(short8*)&lds[cur][1][fA1];
        bh[0] = *(short8*)&lds[cur][2][fB0];  bh[1] = *(short8*)&lds[cur][2][fB1];
        bl[0] = *(short8*)&lds[cur][3][fB0];  bl[1] = *(short8*)&lds[cur][3][fB1];
        #pragma unroll
        for (int mi = 0; mi < 2; ++mi)
            #pragma unroll
            for (int ni = 0; ni < 2; ++ni) {
                acc[mi][ni] = __builtin_amdgcn_mfma_f32_16x16x32_bf16(ah[mi], bh[ni], acc[mi][ni], 0, 0, 0);
                acc[mi][ni] = __builtin_amdgcn_mfma_f32_16x16x32_bf16(al[mi], bh[ni], acc[mi][ni], 0, 0, 0);
                acc[mi][ni] = __builtin_amdgcn_mfma_f32_16x16x32_bf16(ah[mi], bl[ni], acc[mi][ni], 0, 0, 0);
            }
        __syncthreads();   // implicit vmcnt(0) drain completes next-tile staging
    }

    if (MODE == 0 || brow < L_DIM) {
        #pragma unroll
        for (int mi = 0; mi < 2; ++mi) {
            #pragma unroll
            for (int ni = 0; ni < 2; ++ni) {
                const int col   = bcol + wc + ni * 16 + (lane & 15);
                const int rbase = brow + wr + mi * 16 + ((lane >> 4) << 2);
                const float bv = bias[col];
                #pragma unroll
                for (int r = 0; r < 4; ++r) {
                    const float v = acc[mi][ni][r] + bv;
                    const int row = rbase + r;
                    if (MODE == 0) {
                        const float h = fmaxf(v, 0.f);
                        const ushort hh = f2bf(h);
                        OutHi[(size_t)row * D_DIM + col] = hh;
                        OutLo[(size_t)row * D_DIM + col] = f2bf(h - bf2f(hh));
                    } else {
                        OutF[(size_t)row * D_DIM + col] = (cnt[row] > 0.f) ? v : 0.f;
                    }
                }
            }
        }
    } else {
        // anti half: weighted column sums over this block's 64 rows
        float s[2] = {0.f, 0.f};
        #pragma unroll
        for (int mi = 0; mi < 2; ++mi) {
            const int rbase = brow + wr + mi * 16 + ((lane >> 4) << 2);
            #pragma unroll
            for (int r = 0; r < 4; ++r) {
                const float w = (cnt[rbase + r - L_DIM] < 255.5f) ? 1.0f : 0.0f;
                #pragma unroll
                for (int ni = 0; ni < 2; ++ni) {
                    const int col = bcol + wc + ni * 16 + (lane & 15);
                    s[ni] = fmaf(w, acc[mi][ni][r] + bias[col], s[ni]);
                }
            }
        }
        #pragma unroll
        for (int ni = 0; ni < 2; ++ni) {
            s[ni] += __shfl_down(s[ni], 32);
            s[ni] += __shfl_down(s[ni], 16);
            if (lane < 16) colsum[wid][ni * 16 + lane] = s[ni];
        }
        __syncthreads();
        if (tid < 64) {
            const float v = (tid < 32)
                ? colsum[0][tid] + colsum[2][tid]
                : colsum[1][tid - 32] + colsum[3][tid - 32];
            Partial[(size_t)(blockIdx.y - 16) * D_DIM + bcol + tid] = v;
        }
    }
}

// ---------------------------------------------------------------------------
// K4: anti row = (sum of 16 partials per column) / max(wsum, 1)
// ---------------------------------------------------------------------------
__global__ __launch_bounds__(256)
void finalize_anti(const float* __restrict__ Partial,
                   const float* __restrict__ cnt,
                   float* __restrict__ out)
{
    const int d = blockIdx.x * 256 + threadIdx.x;   // 0..767
    float s = 0.f;
    #pragma unroll
    for (int p = 0; p < 16; ++p) s += Partial[(size_t)p * D_DIM + d];
    float wsum = 0.f;
    #pragma unroll 8
    for (int l = 0; l < L_DIM; ++l) wsum += (cnt[l] < 255.5f) ? 1.0f : 0.0f;
    out[(size_t)L_DIM * D_DIM + d] = s / fmaxf(wsum, 1.0f);
}

// ---------------------------------------------------------------------------
extern "C" void kernel_launch(void* const* d_in, const int* in_sizes, int n_in,
                              void* d_out, int out_size, void* d_ws, size_t ws_size,
                              hipStream_t stream) {
    const float* x    = (const float*)d_in[0];
    const int*   mask = (const int*)d_in[1];
    const float* gpt  = (const float*)d_in[2];
    const float* W_h  = (const float*)d_in[3];
    const float* b_h  = (const float*)d_in[4];
    const float* W_p  = (const float*)d_in[5];
    const float* b_p  = (const float*)d_in[6];
    float* out = (float*)d_out;

    char* p = (char*)d_ws;
    ushort* Vhi  = (ushort*)p; p += (size_t)2 * L_DIM * D_DIM * 2;
    ushort* Vlo  = (ushort*)p; p += (size_t)2 * L_DIM * D_DIM * 2;
    ushort* Hhi  = (ushort*)p; p += (size_t)2 * L_DIM * D_DIM * 2;
    ushort* Hlo  = (ushort*)p; p += (size_t)2 * L_DIM * D_DIM * 2;
    ushort* WhHi = (ushort*)p; p += (size_t)768 * 768 * 2;
    ushort* WhLo = (ushort*)p; p += (size_t)768 * 768 * 2;
    ushort* WpHi = (ushort*)p; p += (size_t)768 * 768 * 2;
    ushort* WpLo = (ushort*)p; p += (size_t)768 * 768 * 2;
    float*  Part = (float*)p;  p += (size_t)16 * D_DIM * 4;
    float*  cnt  = (float*)p;

    cast_w<<<(768 * 768 * 2 / 4) / 256, 256, 0, stream>>>(W_h, W_p, WhHi, WhLo, WpHi, WpLo);

    reduce_build_v<<<256, 768, 0, stream>>>(x, mask, gpt, Vhi, Vlo, cnt);

    dim3 ggrid(D_DIM / 64, 2 * L_DIM / 64);
    gemm_split<0><<<ggrid, 256, 0, stream>>>(Vhi, Vlo, WhHi, WhLo, b_h,
                                             Hhi, Hlo, nullptr, nullptr, nullptr);
    gemm_split<1><<<ggrid, 256, 0, stream>>>(Hhi, Hlo, WpHi, WpLo, b_p,
                                             nullptr, nullptr, out, Part, cnt);

    finalize_anti<<<3, 256, 0, stream>>>(Part, cnt, out);
}

// Round 5
// 187.007 us; speedup vs baseline: 1.8283x; 1.1040x over previous
//
#include <hip/hip_runtime.h>

#define L_DIM 1024
#define B_DIM 256
#define D_DIM 768
#define K_DIM 768
#define NT    (K_DIM / 32)
#define WN    (768 * 768)

typedef _Float16 half8 __attribute__((ext_vector_type(8)));
typedef float    floatx4 __attribute__((ext_vector_type(4)));

__device__ __forceinline__ ushort f2h(float f) {
    _Float16 h = (_Float16)f;
    return __builtin_bit_cast(ushort, h);
}
__device__ __forceinline__ float h2f(ushort u) {
    return (float)__builtin_bit_cast(_Float16, u);
}

__device__ __forceinline__ void gl16(const ushort* g, ushort* l) {
    __builtin_amdgcn_global_load_lds(
        (const __attribute__((address_space(1))) unsigned int*)g,
        (__attribute__((address_space(3))) unsigned int*)l, 16, 0, 0);
}

// ---------------------------------------------------------------------------
// K1 fused: blocks 0..255 = reduce over B (4 l-rows per block, nt loads);
//           blocks 256..639 = cast W_h,W_p to f16.
// Reduce emits avg_pos/avg_anti as f16 hi/lo (fp32-accurate pair).
// ---------------------------------------------------------------------------
__global__ __launch_bounds__(768)
void reduce_and_cast(const float* __restrict__ x,
                     const int* __restrict__ mask,
                     const float* __restrict__ gpt,
                     const float* __restrict__ Wh, const float* __restrict__ Wp,
                     ushort* __restrict__ Vhi, ushort* __restrict__ Vlo,
                     ushort* __restrict__ WhH, ushort* __restrict__ WpH,
                     float* __restrict__ pos_cnt)
{
    const int tid = threadIdx.x;

    if (blockIdx.x >= 256) {
        // ---- weight cast: 384 blocks x 768 threads x 4 elems
        const int idx = ((blockIdx.x - 256) * 768 + tid) * 4;
        const float4 v = (idx < WN) ? *(const float4*)(Wh + idx)
                                    : *(const float4*)(Wp + (idx - WN));
        ushort4 o;
        o.x = f2h(v.x); o.y = f2h(v.y); o.z = f2h(v.z); o.w = f2h(v.w);
        if (idx < WN) *(ushort4*)(WhH + idx) = o;
        else          *(ushort4*)(WpH + (idx - WN)) = o;
        return;
    }

    __shared__ int mS[256][4];
    const int l0 = blockIdx.x * 4;
    if (tid < 256)
        *(int4*)&mS[tid][0] = *(const int4*)(mask + (size_t)tid * L_DIM + l0);
    __syncthreads();

    const int row = tid / 192;       // 0..3
    const int t   = tid % 192;
    const int d0  = t * 4;
    const int l   = l0 + row;

    const size_t bstride = (size_t)L_DIM * D_DIM;
    const float* xp = x + (size_t)l * D_DIM + d0;

    floatx4 pos = {0.f, 0.f, 0.f, 0.f};
    floatx4 tot = {0.f, 0.f, 0.f, 0.f};
    float cnt = 0.f;

    #pragma unroll 16
    for (int b = 0; b < B_DIM; ++b) {
        const floatx4 v = __builtin_nontemporal_load((const floatx4*)(xp + (size_t)b * bstride));
        const float fm = (float)mS[b][row];
        tot += v;
        pos[0] = fmaf(fm, v[0], pos[0]);
        pos[1] = fmaf(fm, v[1], pos[1]);
        pos[2] = fmaf(fm, v[2], pos[2]);
        pos[3] = fmaf(fm, v[3], pos[3]);
        cnt += fm;
    }

    const float inv_p = 0.5f / fmaxf(cnt, 1.0f);
    const float inv_a = 0.5f / fmaxf((float)B_DIM - cnt, 1.0f);

    const float4 g4  = *(const float4*)(gpt + (size_t)l * D_DIM + d0);
    const float4 gl4 = *(const float4*)(gpt + (size_t)L_DIM * D_DIM + d0);

    float vp[4], va[4];
    vp[0] = pos[0] * inv_p + 0.5f * g4.x;
    vp[1] = pos[1] * inv_p + 0.5f * g4.y;
    vp[2] = pos[2] * inv_p + 0.5f * g4.z;
    vp[3] = pos[3] * inv_p + 0.5f * g4.w;
    va[0] = (tot[0] - pos[0]) * inv_a + 0.5f * gl4.x;
    va[1] = (tot[1] - pos[1]) * inv_a + 0.5f * gl4.y;
    va[2] = (tot[2] - pos[2]) * inv_a + 0.5f * gl4.z;
    va[3] = (tot[3] - pos[3]) * inv_a + 0.5f * gl4.w;

    ushort4 ph, pl, ah, al;
    ph.x = f2h(vp[0]); pl.x = f2h(vp[0] - h2f(ph.x));
    ph.y = f2h(vp[1]); pl.y = f2h(vp[1] - h2f(ph.y));
    ph.z = f2h(vp[2]); pl.z = f2h(vp[2] - h2f(ph.z));
    ph.w = f2h(vp[3]); pl.w = f2h(vp[3] - h2f(ph.w));
    ah.x = f2h(va[0]); al.x = f2h(va[0] - h2f(ah.x));
    ah.y = f2h(va[1]); al.y = f2h(va[1] - h2f(ah.y));
    ah.z = f2h(va[2]); al.z = f2h(va[2] - h2f(ah.z));
    ah.w = f2h(va[3]); al.w = f2h(va[3] - h2f(ah.w));

    const size_t r0 = (size_t)l * D_DIM + d0;
    const size_t r1 = (size_t)(L_DIM + l) * D_DIM + d0;
    *(ushort4*)(Vhi + r0) = ph;  *(ushort4*)(Vlo + r0) = pl;
    *(ushort4*)(Vhi + r1) = ah;  *(ushort4*)(Vlo + r1) = al;

    if (t == 0) pos_cnt[l] = cnt;
}

// ---------------------------------------------------------------------------
// Split-f16 MFMA GEMM: C = A(f16 hi/lo) @ B(f16)^T + bias.
// 2-term: Ah*Bh + Al*Bh. 64x64 tile, 4 waves (2x2 frags of 16x16x32), BK=32.
// gl_lds staging, LDS double-buffer, XOR-swizzled k-slots (conflict-free
// fragment reads; swizzle applied to the GLOBAL source, LDS dest linear).
// MODE 0: ReLU, emit f16 hi/lo. MODE 1: proto rows -> masked d_out,
// anti rows -> per-block weighted column sums into Partial.
// ---------------------------------------------------------------------------
template<int MODE>
__global__ __launch_bounds__(256)
void gemm_split(const ushort* __restrict__ Ahi, const ushort* __restrict__ Alo,
                const ushort* __restrict__ Bh, const float* __restrict__ bias,
                ushort* __restrict__ OutHi, ushort* __restrict__ OutLo,
                float* __restrict__ OutF, float* __restrict__ Partial,
                const float* __restrict__ cnt)
{
    __shared__ ushort lds[2][3][64 * 32];   // [buf][Ah,Al,Bh][row*32+k]
    __shared__ float  colsum[4][32];

    const int tid  = threadIdx.x;
    const int lane = tid & 63;
    const int wid  = tid >> 6;
    const int brow = blockIdx.y * 64;
    const int bcol = blockIdx.x * 64;
    const int wr   = (wid >> 1) * 32;
    const int wc   = (wid & 1) * 32;

    // staging: thread -> physical (srow, slot); global src k-chunk is swizzled
    const int srow = tid >> 2;
    const int slot = tid & 3;
    const int sk   = (slot ^ ((srow >> 1) & 3)) * 8;

    const ushort* pAh = Ahi + (size_t)(brow + srow) * K_DIM + sk;
    const ushort* pAl = Alo + (size_t)(brow + srow) * K_DIM + sk;
    const ushort* pBh = Bh  + (size_t)(bcol + srow) * K_DIM + sk;

    const int ldst = tid * 8;

    // fragment reads: logical (row, q=lane>>4) -> physical slot q ^ ((row>>1)&3)
    const int q   = lane >> 4;
    const int rA  = wr + (lane & 15);
    const int rB  = wc + (lane & 15);
    const int fA  = rA * 32 + ((q ^ ((rA >> 1) & 3)) << 3);   // +512 for row+16
    const int fB  = rB * 32 + ((q ^ ((rB >> 1) & 3)) << 3);

    floatx4 acc[2][2] = {};

    gl16(pAh, &lds[0][0][ldst]);
    gl16(pAl, &lds[0][1][ldst]);
    gl16(pBh, &lds[0][2][ldst]);
    __syncthreads();

    for (int t = 0; t < NT; ++t) {
        const int cur = t & 1;
        if (t + 1 < NT) {
            const int ko = (t + 1) * 32;
            const int nxt = cur ^ 1;
            gl16(pAh + ko, &lds[nxt][0][ldst]);
            gl16(pAl + ko, &lds[nxt][1][ldst]);
            gl16(pBh + ko, &lds[nxt][2][ldst]);
        }
        half8 ah0 = *(half8*)&lds[cur][0][fA];
        half8 ah1 = *(half8*)&lds[cur][0][fA + 512];
        half8 al0 = *(half8*)&lds[cur][1][fA];
        half8 al1 = *(half8*)&lds[cur][1][fA + 512];
        half8 bh0 = *(half8*)&lds[cur][2][fB];
        half8 bh1 = *(half8*)&lds[cur][2][fB + 512];

        acc[0][0] = __builtin_amdgcn_mfma_f32_16x16x32_f16(ah0, bh0, acc[0][0], 0, 0, 0);
        acc[0][1] = __builtin_amdgcn_mfma_f32_16x16x32_f16(ah0, bh1, acc[0][1], 0, 0, 0);
        acc[1][0] = __builtin_amdgcn_mfma_f32_16x16x32_f16(ah1, bh0, acc[1][0], 0, 0, 0);
        acc[1][1] = __builtin_amdgcn_mfma_f32_16x16x32_f16(ah1, bh1, acc[1][1], 0, 0, 0);
        acc[0][0] = __builtin_amdgcn_mfma_f32_16x16x32_f16(al0, bh0, acc[0][0], 0, 0, 0);
        acc[0][1] = __builtin_amdgcn_mfma_f32_16x16x32_f16(al0, bh1, acc[0][1], 0, 0, 0);
        acc[1][0] = __builtin_amdgcn_mfma_f32_16x16x32_f16(al1, bh0, acc[1][0], 0, 0, 0);
        acc[1][1] = __builtin_amdgcn_mfma_f32_16x16x32_f16(al1, bh1, acc[1][1], 0, 0, 0);

        __syncthreads();   // drains gl_lds (vmcnt0) + protects cur buffer
    }

    if (MODE == 0 || brow < L_DIM) {
        #pragma unroll
        for (int mi = 0; mi < 2; ++mi) {
            #pragma unroll
            for (int ni = 0; ni < 2; ++ni) {
                const int col   = bcol + wc + ni * 16 + (lane & 15);
                const int rbase = brow + wr + mi * 16 + ((lane >> 4) << 2);
                const float bv = bias[col];
                #pragma unroll
                for (int r = 0; r < 4; ++r) {
                    const float v = acc[mi][ni][r] + bv;
                    const int row = rbase + r;
                    if (MODE == 0) {
                        const float h = fmaxf(v, 0.f);
                        const ushort hh = f2h(h);
                        OutHi[(size_t)row * D_DIM + col] = hh;
                        OutLo[(size_t)row * D_DIM + col] = f2h(h - h2f(hh));
                    } else {
                        OutF[(size_t)row * D_DIM + col] = (cnt[row] > 0.f) ? v : 0.f;
                    }
                }
            }
        }
    } else {
        float s[2] = {0.f, 0.f};
        #pragma unroll
        for (int mi = 0; mi < 2; ++mi) {
            const int rbase = brow + wr + mi * 16 + ((lane >> 4) << 2);
            #pragma unroll
            for (int r = 0; r < 4; ++r) {
                const float w = (cnt[rbase + r - L_DIM] < 255.5f) ? 1.0f : 0.0f;
                #pragma unroll
                for (int ni = 0; ni < 2; ++ni) {
                    const int col = bcol + wc + ni * 16 + (lane & 15);
                    s[ni] = fmaf(w, acc[mi][ni][r] + bias[col], s[ni]);
                }
            }
        }
        #pragma unroll
        for (int ni = 0; ni < 2; ++ni) {
            s[ni] += __shfl_down(s[ni], 32);
            s[ni] += __shfl_down(s[ni], 16);
            if (lane < 16) colsum[wid][ni * 16 + lane] = s[ni];
        }
        __syncthreads();
        if (tid < 64) {
            const float v = (tid < 32)
                ? colsum[0][tid] + colsum[2][tid]
                : colsum[1][tid - 32] + colsum[3][tid - 32];
            Partial[(size_t)(blockIdx.y - 16) * D_DIM + bcol + tid] = v;
        }
    }
}

// ---------------------------------------------------------------------------
// K4: anti row = (sum of 16 partials per column) / max(wsum, 1)
// ---------------------------------------------------------------------------
__global__ __launch_bounds__(256)
void finalize_anti(const float* __restrict__ Partial,
                   const float* __restrict__ cnt,
                   float* __restrict__ out)
{
    const int d = blockIdx.x * 256 + threadIdx.x;
    float s = 0.f;
    #pragma unroll
    for (int p = 0; p < 16; ++p) s += Partial[(size_t)p * D_DIM + d];
    float wsum = 0.f;
    #pragma unroll 8
    for (int l = 0; l < L_DIM; ++l) wsum += (cnt[l] < 255.5f) ? 1.0f : 0.0f;
    out[(size_t)L_DIM * D_DIM + d] = s / fmaxf(wsum, 1.0f);
}

// ---------------------------------------------------------------------------
extern "C" void kernel_launch(void* const* d_in, const int* in_sizes, int n_in,
                              void* d_out, int out_size, void* d_ws, size_t ws_size,
                              hipStream_t stream) {
    const float* x    = (const float*)d_in[0];
    const int*   mask = (const int*)d_in[1];
    const float* gpt  = (const float*)d_in[2];
    const float* W_h  = (const float*)d_in[3];
    const float* b_h  = (const float*)d_in[4];
    const float* W_p  = (const float*)d_in[5];
    const float* b_p  = (const float*)d_in[6];
    float* out = (float*)d_out;

    char* p = (char*)d_ws;
    ushort* Vhi  = (ushort*)p; p += (size_t)2 * L_DIM * D_DIM * 2;
    ushort* Vlo  = (ushort*)p; p += (size_t)2 * L_DIM * D_DIM * 2;
    ushort* Hhi  = (ushort*)p; p += (size_t)2 * L_DIM * D_DIM * 2;
    ushort* Hlo  = (ushort*)p; p += (size_t)2 * L_DIM * D_DIM * 2;
    ushort* WhH  = (ushort*)p; p += (size_t)WN * 2;
    ushort* WpH  = (ushort*)p; p += (size_t)WN * 2;
    float*  Part = (float*)p;  p += (size_t)16 * D_DIM * 4;
    float*  cnt  = (float*)p;

    reduce_and_cast<<<640, 768, 0, stream>>>(x, mask, gpt, W_h, W_p,
                                             Vhi, Vlo, WhH, WpH, cnt);

    dim3 ggrid(D_DIM / 64, 2 * L_DIM / 64);
    gemm_split<0><<<ggrid, 256, 0, stream>>>(Vhi, Vlo, WhH, b_h,
                                             Hhi, Hlo, nullptr, nullptr, nullptr);
    gemm_split<1><<<ggrid, 256, 0, stream>>>(Hhi, Hlo, WpH, b_p,
                                             nullptr, nullptr, out, Part, cnt);

    finalize_anti<<<3, 256, 0, stream>>>(Part, cnt, out);
}